// Round 4
// baseline (540.603 us; speedup 1.0000x reference)
//
#include <hip/hip_runtime.h>
#include <stdint.h>

// Problem constants (from reference)
#define HH 176
#define WW 200
#define BB 4
#define CIN 128
#define COUT 256
#define NPTS (4096 * 64)            // 262144 points
#define CELLS (BB * WW * HH)        // 140800 cells
#define FEAT_OUT_ELEMS ((size_t)NPTS * COUT)  // 67108864
#define CAP 32                      // max points/cell tracked (Poisson lambda~1.6 -> max ~12)
#define TCELLS 32                   // cells per fused block
#define LDSWF 132                   // padded stride (f32 words / ushorts): conflict-free b128 frag reads
#define LDSW16 260                  // ushort stride for transposed out tile
#define FLATCAP 1024                // 32 cells x CAP hard bound

typedef __attribute__((ext_vector_type(8))) short bf16x8;
typedef __attribute__((ext_vector_type(4))) float f32x4;

// ---------- bf16 helpers (RNE) ----------
__device__ __forceinline__ unsigned short f2bf(float f) {
    union { float f; unsigned int u; } c; c.f = f;
    unsigned int u = c.u;
    u += 0x7fffu + ((u >> 16) & 1u);
    return (unsigned short)(u >> 16);
}
__device__ __forceinline__ float bf2f(unsigned int h16) {
    union { unsigned int u; float f; } c; c.u = h16 << 16;
    return c.f;
}

// ---------- 0. prep: zero counts + convert W to bf16 (replaces memset + wcvt) ----------
__global__ __launch_bounds__(256) void prep_kernel(
    const float* __restrict__ lw, unsigned short* __restrict__ wb,
    int* __restrict__ counts)
{
    int i = blockIdx.x * 256 + threadIdx.x;   // grid 550 -> i < 140800
    if (i < COUT * CIN) wb[i] = f2bf(lw[i]);
    counts[i] = 0;
}

// ---------- 1. build: per-cell lists + index echo + zero invalid output rows ----------
__global__ __launch_bounds__(256) void build_kernel(
    const int* __restrict__ idx, int* __restrict__ counts, int* __restrict__ plist,
    float* __restrict__ out_idx, float* __restrict__ out_feats)
{
    __shared__ unsigned char validf[256];
    int tid = threadIdx.x;
    int p0 = blockIdx.x * 256;
    int p = p0 + tid;
    int b = idx[3 * p], x = idx[3 * p + 1], y = idx[3 * p + 2];
    out_idx[3 * p]     = (float)b;
    out_idx[3 * p + 1] = (float)x;
    out_idx[3 * p + 2] = (float)y;
    bool valid = ((unsigned)x < HH && (unsigned)y < WW);
    validf[tid] = valid ? 1 : 0;
    if (valid) {
        int cell = (b * WW + y) * HH + x;
        int slot = atomicAdd(&counts[cell], 1);
        if (slot < CAP) plist[(size_t)cell * CAP + slot] = p;
    }
    __syncthreads();
    // cooperatively zero the 256-ch output rows of this block's invalid points
    int w = tid >> 6, lane = tid & 63;
    float4 z = { 0.0f, 0.0f, 0.0f, 0.0f };
    for (int v = w; v < 256; v += 4)
        if (!validf[v])
            *(float4*)(out_feats + (size_t)(p0 + v) * COUT + lane * 4) = z;
}

// ---------- 2. fused: per-cell sum (LDS atomics) + LN + MFMA GEMM + scatter ----------
// Block = 32 cells x 256 outputs, 4 waves. The block's flat point list drives both
// the accumulate phase (independent feats-row loads, 2-deep software pipeline; LDS
// f32 atomics resolve same-cell collisions) and the final scatter. normed never
// leaves LDS; out-tile LDS aliases the dead accumulator. LDS ~30.6 KB -> 5 blocks/CU.
__global__ __launch_bounds__(256) void fused_kernel(
    const float* __restrict__ feats,
    const unsigned short* __restrict__ Wb,   // [256][128] bf16
    const int* __restrict__ counts,
    const int* __restrict__ plist,
    const float* __restrict__ nw, const float* __restrict__ nb,
    float* __restrict__ out)                 // [NPTS][256] f32
{
    __shared__ float accf[TCELLS * LDSWF];              // 16,896 B; later aliased as out16
    __shared__ unsigned short normedl[TCELLS * LDSWF];  // 8,448 B
    __shared__ int fpid[FLATCAP];                       // 4 KB
    __shared__ unsigned char fcell[FLATCAP];            // 1 KB
    __shared__ int scnt[TCELLS];
    __shared__ int nflat;
    unsigned short* out16 = (unsigned short*)accf;      // [TCELLS][LDSW16] (16,640 B)

    int tid = threadIdx.x;
    int w = tid >> 6, lane = tid & 63;
    int l15 = lane & 15, g = lane >> 4;
    int kgrp = g * 8, orow = g * 4;
    int c0 = blockIdx.x * TCELLS;

    if (tid == 0) nflat = 0;
    if (tid < TCELLS) {
        int cnt = counts[c0 + tid];
        scnt[tid] = cnt < CAP ? cnt : CAP;
    }
    for (int i = tid; i < TCELLS * LDSWF; i += 256) accf[i] = 0.0f;
    __syncthreads();

    // build the block's flat (pid, cell) list
    if (tid < TCELLS) {
        int cnt = scnt[tid];
        if (cnt > 0) {
            int base = atomicAdd(&nflat, cnt);
            for (int s = 0; s < cnt; ++s) {
                fpid[base + s] = plist[(size_t)(c0 + tid) * CAP + s];
                fcell[base + s] = (unsigned char)tid;
            }
        }
    }
    __syncthreads();
    int nt = nflat;

    // ---- accumulate: independent row loads, 2-deep software pipeline ----
    {
        int k = w;
        float2 v0 = {0.0f, 0.0f};
        int cc0 = 0;
        if (k < nt) {
            int pid = fpid[k]; cc0 = fcell[k];
            v0 = *(const float2*)(feats + (size_t)pid * CIN + lane * 2);
        }
        while (k < nt) {
            int kn = k + 4;
            float2 v1 = {0.0f, 0.0f};
            int cc1 = 0;
            if (kn < nt) {
                int pid = fpid[kn]; cc1 = fcell[kn];
                v1 = *(const float2*)(feats + (size_t)pid * CIN + lane * 2);
            }
            atomicAdd(&accf[cc0 * LDSWF + lane * 2], v0.x);
            atomicAdd(&accf[cc0 * LDSWF + lane * 2 + 1], v0.y);
            k = kn; cc0 = cc1; v0 = v1;
        }
    }

    // preload W fragments (L2-hot 64 KB buffer); issue before the barrier so the
    // loads overlap the accumulate drain + LN
    bf16x8 a[4][4];
    #pragma unroll
    for (int i = 0; i < 4; ++i)
        #pragma unroll
        for (int kk = 0; kk < 4; ++kk)
            a[i][kk] = *(const bf16x8*)(Wb + (size_t)(((w * 4 + i) * 16 + l15) * CIN) + kgrp + kk * 32);

    float w0 = nw[lane * 2], w1 = nw[lane * 2 + 1];
    float b0 = nb[lane * 2], b1 = nb[lane * 2 + 1];

    __syncthreads();

    // ---- layernorm per cell (wave w: cells w, w+4, ...) ----
    for (int c = w; c < TCELLS; c += 4) {
        float a0 = accf[c * LDSWF + lane * 2];
        float a1 = accf[c * LDSWF + lane * 2 + 1];
        float s = a0 + a1;
        float ss = a0 * a0 + a1 * a1;
        #pragma unroll
        for (int m = 32; m >= 1; m >>= 1) {
            s  += __shfl_xor(s, m, 64);
            ss += __shfl_xor(ss, m, 64);
        }
        float mu  = s * (1.0f / 128.0f);
        float var = ss * (1.0f / 128.0f) - mu * mu;
        float inv = rsqrtf(var + 1e-5f);
        ushort2 st;
        st.x = f2bf((a0 - mu) * inv * w0 + b0);
        st.y = f2bf((a1 - mu) * inv * w1 + b1);
        *(ushort2*)(&normedl[c * LDSWF + lane * 2]) = st;
    }
    __syncthreads();   // normedl ready; accf reads done -> out16 alias safe

    // ---- MFMA: 2 cell sub-tiles, wave w owns o-band [w*64, w*64+64) ----
    #pragma unroll
    for (int tj = 0; tj < 2; ++tj) {
        bf16x8 bb[4];
        #pragma unroll
        for (int kk = 0; kk < 4; ++kk)
            bb[kk] = *(const bf16x8*)(normedl + (tj * 16 + l15) * LDSWF + kgrp + kk * 32);
        f32x4 acc[4];
        #pragma unroll
        for (int i = 0; i < 4; ++i) acc[i] = (f32x4){0.0f, 0.0f, 0.0f, 0.0f};
        #pragma unroll
        for (int kk = 0; kk < 4; ++kk)
            #pragma unroll
            for (int i = 0; i < 4; ++i)
                acc[i] = __builtin_amdgcn_mfma_f32_16x16x32_bf16(a[i][kk], bb[kk], acc[i], 0, 0, 0);
        // C/D layout: col(cell)=lane&15, row(o)=(lane>>4)*4+reg
        #pragma unroll
        for (int i = 0; i < 4; ++i) {
            int o = w * 64 + i * 16 + orow;
            ushort4 st;
            st.x = f2bf(acc[i][0]);
            st.y = f2bf(acc[i][1]);
            st.z = f2bf(acc[i][2]);
            st.w = f2bf(acc[i][3]);
            *(ushort4*)(&out16[(tj * 16 + l15) * LDSW16 + o]) = st;
        }
    }
    __syncthreads();

    // ---- scatter: one float4 quarter-row per lane per point ----
    for (int k = w; k < nt; k += 4) {
        int pid = fpid[k];
        int c = fcell[k];
        ushort4 v = *(const ushort4*)(&out16[c * LDSW16 + lane * 4]);
        float4 o4;
        o4.x = bf2f(v.x);
        o4.y = bf2f(v.y);
        o4.z = bf2f(v.z);
        o4.w = bf2f(v.w);
        *(float4*)(out + (size_t)pid * COUT + lane * 4) = o4;
    }
}

extern "C" void kernel_launch(void* const* d_in, const int* in_sizes, int n_in,
                              void* d_out, int out_size, void* d_ws, size_t ws_size,
                              hipStream_t stream)
{
    const float* feats = (const float*)d_in[0];
    const int*   idx   = (const int*)d_in[1];
    const float* nw    = (const float*)d_in[2];
    const float* nb    = (const float*)d_in[3];
    const float* lw    = (const float*)d_in[4];
    float* out = (float*)d_out;

    char* ws = (char*)d_ws;
    int* counts = (int*)ws;                                        // 0.56 MB
    int* plist  = (int*)(ws + (1u << 20));                         // 18 MB
    unsigned short* wb     = (unsigned short*)(ws + (20u << 20));  // 64 KB bf16

    prep_kernel<<<CELLS / 256, 256, 0, stream>>>(lw, wb, counts);
    build_kernel<<<NPTS / 256, 256, 0, stream>>>(idx, counts, plist, out + FEAT_OUT_ELEMS, out);
    fused_kernel<<<CELLS / TCELLS, 256, 0, stream>>>(feats, wb, counts, plist, nw, nb, out);
}

// Round 5
// 472.968 us; speedup vs baseline: 1.1430x; 1.1430x over previous
//
#include <hip/hip_runtime.h>
#include <stdint.h>

// Problem constants (from reference)
#define HH 176
#define WW 200
#define BB 4
#define CIN 128
#define COUT 256
#define NPTS (4096 * 64)            // 262144 points (pid fits in 18 bits)
#define CELLS (BB * WW * HH)        // 140800 cells
#define FEAT_OUT_ELEMS ((size_t)NPTS * COUT)  // 67108864
#define CAP 32                      // max points/cell tracked (Poisson lambda~1.6 -> max ~12)
#define TCELLS 32                   // cells per fused block
#define LDSWN 132                   // normedl ushort stride (conflict-ok b128 frag reads, measured)
#define LDSWO 260                   // out16 ushort stride
#define FLATCAP 512                 // block flat list bound (nt ~ 51 +/- 7; 65 sigma margin)
#define PIDMASK 0x3FFFF

typedef __attribute__((ext_vector_type(8))) short bf16x8;
typedef __attribute__((ext_vector_type(4))) float f32x4;

// ---------- bf16 helpers (RNE) ----------
__device__ __forceinline__ unsigned short f2bf(float f) {
    union { float f; unsigned int u; } c; c.f = f;
    unsigned int u = c.u;
    u += 0x7fffu + ((u >> 16) & 1u);
    return (unsigned short)(u >> 16);
}
__device__ __forceinline__ float bf2f(unsigned int h16) {
    union { unsigned int u; float f; } c; c.u = h16 << 16;
    return c.f;
}

// ---------- 0. prep: zero counts + convert W to bf16 ----------
__global__ __launch_bounds__(256) void prep_kernel(
    const float* __restrict__ lw, unsigned short* __restrict__ wb,
    int* __restrict__ counts)
{
    int i = blockIdx.x * 256 + threadIdx.x;   // grid 550 -> i < 140800
    if (i < COUT * CIN) wb[i] = f2bf(lw[i]);
    counts[i] = 0;
}

// ---------- 1. build: per-cell lists + index echo + zero invalid output rows ----------
__global__ __launch_bounds__(256) void build_kernel(
    const int* __restrict__ idx, int* __restrict__ counts, int* __restrict__ plist,
    float* __restrict__ out_idx, float* __restrict__ out_feats)
{
    __shared__ unsigned char validf[256];
    int tid = threadIdx.x;
    int p0 = blockIdx.x * 256;
    int p = p0 + tid;
    int b = idx[3 * p], x = idx[3 * p + 1], y = idx[3 * p + 2];
    out_idx[3 * p]     = (float)b;
    out_idx[3 * p + 1] = (float)x;
    out_idx[3 * p + 2] = (float)y;
    bool valid = ((unsigned)x < HH && (unsigned)y < WW);
    validf[tid] = valid ? 1 : 0;
    if (valid) {
        int cell = (b * WW + y) * HH + x;
        int slot = atomicAdd(&counts[cell], 1);
        if (slot < CAP) plist[(size_t)cell * CAP + slot] = p;
    }
    __syncthreads();
    // cooperatively zero the 256-ch output rows of this block's invalid points
    int w = tid >> 6, lane = tid & 63;
    float4 z = { 0.0f, 0.0f, 0.0f, 0.0f };
    for (int v = w; v < 256; v += 4)
        if (!validf[v])
            *(float4*)(out_feats + (size_t)(p0 + v) * COUT + lane * 4) = z;
}

// ---------- 2. fused v3: register accumulate + LN + MFMA + scatter ----------
// Block = 32 cells, 4 waves, 3 barriers. Wave w owns cells {w+4j}.
// Flat list built in ONE parallel step (int4/lane) by wave 0; bases via a
// redundant per-wave shuffle scan (no extra barrier). Accumulate stages 4
// cells' pid-int4s then issues <=4 independent guarded row loads per cell
// (4-16 loads in flight vs 1 before); LN entirely in registers.
// LDS 27.3 KB; no LDS atomics; no accf zero-init.
__global__ __launch_bounds__(256) void fused_kernel(
    const float* __restrict__ feats,
    const unsigned short* __restrict__ Wb,   // [256][128] bf16
    const int* __restrict__ counts,
    const int* __restrict__ plist,
    const float* __restrict__ nw, const float* __restrict__ nb,
    float* __restrict__ out)                 // [NPTS][256] f32
{
    __shared__ unsigned short normedl[TCELLS * LDSWN];  // 8448 B
    __shared__ unsigned short out16[TCELLS * LDSWO];    // 16640 B
    __shared__ int fpl[FLATCAP];                        // 2048 B: pid | cell<<18
    __shared__ int scnt[TCELLS];                        // 128 B

    int tid = threadIdx.x;
    int w = tid >> 6, lane = tid & 63;
    int l15 = lane & 15, g = lane >> 4;
    int kgrp = g * 8, orow = g * 4;
    int c0 = blockIdx.x * TCELLS;

    if (tid < 8) {
        int4 c4 = *(const int4*)(counts + c0 + tid * 4);
        scnt[tid * 4 + 0] = c4.x < CAP ? c4.x : CAP;
        scnt[tid * 4 + 1] = c4.y < CAP ? c4.y : CAP;
        scnt[tid * 4 + 2] = c4.z < CAP ? c4.z : CAP;
        scnt[tid * 4 + 3] = c4.w < CAP ? c4.w : CAP;
    }
    float w0 = nw[lane * 2], w1 = nw[lane * 2 + 1];   // tiny, L2-hot
    float b0 = nb[lane * 2], b1 = nb[lane * 2 + 1];
    __syncthreads();   // #1: scnt visible

    // every wave: inclusive shuffle-scan of scnt over lanes 0..31 (both halves
    // compute the same scan independently -> no cross-half dependence)
    int l31 = lane & 31;
    int cs = scnt[l31];
    int v = cs;
    #pragma unroll
    for (int off = 1; off < 32; off <<= 1) {
        int t = __shfl_up(v, off, 64);
        if (l31 >= off) v += t;
    }
    int nt = __shfl(v, 31, 64);          // block total
    if (nt > FLATCAP) nt = FLATCAP;
    int myexcl = v - cs;                 // exclusive base for cell l31

    // wave 0: build packed flat list. lanes 0-31: slots 0-3 (one int4 each);
    // lanes 32-63: slots 4-7 (+rare tail). One memory latency, fully parallel.
    if (tid < 64) {
        int cell = l31;
        int cnt = cs;
        int base = myexcl;
        int tag = cell << 18;
        if (lane < 32) {
            int4 p4 = *(const int4*)(plist + (size_t)(c0 + cell) * CAP);
            if (cnt > 0 && base + 0 < FLATCAP) fpl[base + 0] = (p4.x & PIDMASK) | tag;
            if (cnt > 1 && base + 1 < FLATCAP) fpl[base + 1] = (p4.y & PIDMASK) | tag;
            if (cnt > 2 && base + 2 < FLATCAP) fpl[base + 2] = (p4.z & PIDMASK) | tag;
            if (cnt > 3 && base + 3 < FLATCAP) fpl[base + 3] = (p4.w & PIDMASK) | tag;
        } else if (cnt > 4) {
            int4 p4 = *(const int4*)(plist + (size_t)(c0 + cell) * CAP + 4);
            if (base + 4 < FLATCAP)            fpl[base + 4] = (p4.x & PIDMASK) | tag;
            if (cnt > 5 && base + 5 < FLATCAP) fpl[base + 5] = (p4.y & PIDMASK) | tag;
            if (cnt > 6 && base + 6 < FLATCAP) fpl[base + 6] = (p4.z & PIDMASK) | tag;
            if (cnt > 7 && base + 7 < FLATCAP) fpl[base + 7] = (p4.w & PIDMASK) | tag;
            for (int s = 8; s < cnt; ++s) {    // ultra-rare (P ~ 1e-4)
                int pp = plist[(size_t)(c0 + cell) * CAP + s];
                if (base + s < FLATCAP) fpl[base + s] = (pp & PIDMASK) | tag;
            }
        }
    }

    // ---- accumulate + LN, fully in registers; 2 groups x 4 cells ----
    #pragma unroll
    for (int grp = 0; grp < 2; ++grp) {
        int4 pq[4];
        #pragma unroll
        for (int ci = 0; ci < 4; ++ci) {
            int c = w + (grp * 4 + ci) * 4;
            pq[ci] = *(const int4*)(plist + (size_t)(c0 + c) * CAP);
        }
        #pragma unroll
        for (int ci = 0; ci < 4; ++ci) {
            int c = w + (grp * 4 + ci) * 4;
            int cnt = scnt[c];
            float s0 = 0.0f, s1 = 0.0f;
            if (cnt > 0) { float2 t = *(const float2*)(feats + (size_t)(pq[ci].x) * CIN + lane * 2); s0 += t.x; s1 += t.y; }
            if (cnt > 1) { float2 t = *(const float2*)(feats + (size_t)(pq[ci].y) * CIN + lane * 2); s0 += t.x; s1 += t.y; }
            if (cnt > 2) { float2 t = *(const float2*)(feats + (size_t)(pq[ci].z) * CIN + lane * 2); s0 += t.x; s1 += t.y; }
            if (cnt > 3) { float2 t = *(const float2*)(feats + (size_t)(pq[ci].w) * CIN + lane * 2); s0 += t.x; s1 += t.y; }
            if (cnt > 4) {                     // ~2% of cells, wave-uniform branch
                int4 q2 = *(const int4*)(plist + (size_t)(c0 + c) * CAP + 4);
                { float2 t = *(const float2*)(feats + (size_t)(q2.x) * CIN + lane * 2); s0 += t.x; s1 += t.y; }
                if (cnt > 5) { float2 t = *(const float2*)(feats + (size_t)(q2.y) * CIN + lane * 2); s0 += t.x; s1 += t.y; }
                if (cnt > 6) { float2 t = *(const float2*)(feats + (size_t)(q2.z) * CIN + lane * 2); s0 += t.x; s1 += t.y; }
                if (cnt > 7) { float2 t = *(const float2*)(feats + (size_t)(q2.w) * CIN + lane * 2); s0 += t.x; s1 += t.y; }
                for (int s = 8; s < cnt; ++s) {
                    int pid = plist[(size_t)(c0 + c) * CAP + s];
                    float2 t = *(const float2*)(feats + (size_t)pid * CIN + lane * 2);
                    s0 += t.x; s1 += t.y;
                }
            }
            // layernorm in-register
            float s = s0 + s1, ss = s0 * s0 + s1 * s1;
            #pragma unroll
            for (int m = 32; m >= 1; m >>= 1) {
                s  += __shfl_xor(s, m, 64);
                ss += __shfl_xor(ss, m, 64);
            }
            float mu  = s * (1.0f / 128.0f);
            float var = ss * (1.0f / 128.0f) - mu * mu;
            float inv = rsqrtf(var + 1e-5f);
            ushort2 st;
            st.x = f2bf((s0 - mu) * inv * w0 + b0);
            st.y = f2bf((s1 - mu) * inv * w1 + b1);
            *(ushort2*)(&normedl[c * LDSWN + lane * 2]) = st;
        }
    }
    __syncthreads();   // #2: normedl + fpl ready

    // ---- MFMA: 2 cell sub-tiles; W-frags re-read from L2-hot wb (VGPR-light) ----
    #pragma unroll
    for (int tj = 0; tj < 2; ++tj) {
        f32x4 acc[4];
        #pragma unroll
        for (int i = 0; i < 4; ++i) acc[i] = (f32x4){0.0f, 0.0f, 0.0f, 0.0f};
        #pragma unroll
        for (int kk = 0; kk < 4; ++kk) {
            bf16x8 bbv = *(const bf16x8*)(&normedl[(tj * 16 + l15) * LDSWN + kgrp + kk * 32]);
            #pragma unroll
            for (int i = 0; i < 4; ++i) {
                bf16x8 av = *(const bf16x8*)(Wb + (size_t)(((w * 4 + i) * 16 + l15) * CIN) + kgrp + kk * 32);
                acc[i] = __builtin_amdgcn_mfma_f32_16x16x32_bf16(av, bbv, acc[i], 0, 0, 0);
            }
        }
        // C/D layout: col(cell)=lane&15, row(o)=(lane>>4)*4+reg
        #pragma unroll
        for (int i = 0; i < 4; ++i) {
            int o = w * 64 + i * 16 + orow;
            ushort4 st;
            st.x = f2bf(acc[i][0]);
            st.y = f2bf(acc[i][1]);
            st.z = f2bf(acc[i][2]);
            st.w = f2bf(acc[i][3]);
            *(ushort4*)(&out16[(tj * 16 + l15) * LDSWO + o]) = st;
        }
    }
    __syncthreads();   // #3: out16 ready

    // ---- scatter: one float4 quarter-row per lane per point ----
    for (int k = w; k < nt; k += 4) {
        int vpk = fpl[k];
        int pid = vpk & PIDMASK;
        int c = vpk >> 18;
        ushort4 vv = *(const ushort4*)(&out16[c * LDSWO + lane * 4]);
        float4 o4;
        o4.x = bf2f(vv.x);
        o4.y = bf2f(vv.y);
        o4.z = bf2f(vv.z);
        o4.w = bf2f(vv.w);
        *(float4*)(out + (size_t)pid * COUT + lane * 4) = o4;
    }
}

extern "C" void kernel_launch(void* const* d_in, const int* in_sizes, int n_in,
                              void* d_out, int out_size, void* d_ws, size_t ws_size,
                              hipStream_t stream)
{
    const float* feats = (const float*)d_in[0];
    const int*   idx   = (const int*)d_in[1];
    const float* nw    = (const float*)d_in[2];
    const float* nb    = (const float*)d_in[3];
    const float* lw    = (const float*)d_in[4];
    float* out = (float*)d_out;

    char* ws = (char*)d_ws;
    int* counts = (int*)ws;                                        // 0.56 MB
    int* plist  = (int*)(ws + (1u << 20));                         // 18 MB
    unsigned short* wb     = (unsigned short*)(ws + (20u << 20));  // 64 KB bf16

    prep_kernel<<<CELLS / 256, 256, 0, stream>>>(lw, wb, counts);
    build_kernel<<<NPTS / 256, 256, 0, stream>>>(idx, counts, plist, out + FEAT_OUT_ELEMS, out);
    fused_kernel<<<CELLS / TCELLS, 256, 0, stream>>>(feats, wb, counts, plist, nw, nb, out);
}